// Round 3
// baseline (5735.210 us; speedup 1.0000x reference)
//
#include <hip/hip_runtime.h>
#include <math.h>

// DeepArcNet fused kernel, R3: spill-free live-set (~150 floats peak).
//  - q,k never materialized: per output o, qd/kd are 68-FMA dots consumed
//    immediately into wei[2][6] via 6 shfls (score phase live ~= 85 regs).
//  - v streamed the same way into attn[68].
//  - proj+residual and ff2+residual write IN PLACE into h.
//  - launch_bounds(256,1): let allocator use ~200 VGPRs (R2's (256,2)
//    forced a 128-VGPR cap -> 837 MB scratch writes).
// One wave = 10 items, one lane = (item, token c in 0..5). No LDS tiles,
// no barriers; cross-token traffic via __shfl within the wave.

#define EMBD 68
#define NTOK 6
#define HEADD 34

__device__ __forceinline__ float dot68(const float (&h)[EMBD],
                                       const float* __restrict__ w) {
    // 4 accumulators to break the FMA dependence chain.
    float a0 = 0.f, a1 = 0.f, a2 = 0.f, a3 = 0.f;
#pragma unroll
    for (int e = 0; e < 68; e += 4) {
        a0 = fmaf(h[e + 0], w[e + 0], a0);
        a1 = fmaf(h[e + 1], w[e + 1], a1);
        a2 = fmaf(h[e + 2], w[e + 2], a2);
        a3 = fmaf(h[e + 3], w[e + 3], a3);
    }
    return (a0 + a1) + (a2 + a3);
}

__device__ __forceinline__ void ln68_ip(float (&v)[EMBD],
                                        const float* __restrict__ g,
                                        const float* __restrict__ b) {
    float s1 = 0.f;
#pragma unroll
    for (int e = 0; e < EMBD; ++e) s1 += v[e];
    const float m = s1 * (1.0f / 68.0f);
    float s2 = 0.f;
#pragma unroll
    for (int e = 0; e < EMBD; ++e) { const float d = v[e] - m; s2 = fmaf(d, d, s2); }
    const float rs = rsqrtf(s2 * (1.0f / 68.0f) + 1e-5f);
#pragma unroll
    for (int e = 0; e < EMBD; ++e) v[e] = (v[e] - m) * rs * g[e] + b[e];
}

__global__ __launch_bounds__(256, 1)
void deeparcnet_fused(const float* __restrict__ x,        // [B,6,37,5]
                      const float* __restrict__ conv_w,   // [6,1,5,5]
                      const float* __restrict__ conv_b,   // [6]
                      const float* __restrict__ lemb_w,   // [6,4]
                      const float* __restrict__ lemb_b,   // [6,4]
                      const float* __restrict__ wq,       // [2,2,34,68]
                      const float* __restrict__ wk,
                      const float* __restrict__ wv,
                      const float* __restrict__ proj_w,   // [2,68,68]
                      const float* __restrict__ proj_b,   // [2,68]
                      const float* __restrict__ ff1_w,    // [2,34,68]
                      const float* __restrict__ ff1_b,    // [2,34]
                      const float* __restrict__ ff2_w,    // [2,68,34]
                      const float* __restrict__ ff2_b,    // [2,68]
                      const float* __restrict__ ln1_g, const float* __restrict__ ln1_b,
                      const float* __restrict__ ln2_g, const float* __restrict__ ln2_b,
                      const float* __restrict__ lnf_g, const float* __restrict__ lnf_b,
                      const float* __restrict__ fc_w,     // [6,408]
                      const float* __restrict__ fc_b,     // [6]
                      float* __restrict__ out,            // [B,6]
                      int B)
{
    const int lane = threadIdx.x & 63;
    const int wid  = blockIdx.x * (blockDim.x >> 6) + (threadIdx.x >> 6);
    const int sub  = lane / 6;          // item slot in wave: 0..10
    const int c    = lane - sub * 6;    // token / conv channel: 0..5
    const int item = wid * 10 + sub;
    const bool active = (sub < 10) && (item < B);
    const int it = active ? item : 0;   // clamp for safe loads
    const int base_lane = sub * 6;

    // ---------------- conv encode + embed + pos -> h[68] -------------------
    float h[EMBD];
    {
        float xw[25];
#pragma unroll
        for (int k = 0; k < 25; ++k) xw[k] = conv_w[c * 25 + k];
        const float cb = conv_b[c];
        const float* xp = x + (size_t)(it * 6 + c) * 185;

        const float lw0 = lemb_w[c * 4 + 0], lw1 = lemb_w[c * 4 + 1];
        const float lw2 = lemb_w[c * 4 + 2], lw3 = lemb_w[c * 4 + 3];
        const float lb0 = lemb_b[c * 4 + 0], lb1 = lemb_b[c * 4 + 1];
        const float lb2 = lemb_b[c * 4 + 2], lb3 = lemb_b[c * 4 + 3];

#pragma unroll
        for (int t = 0; t < 17; ++t) {
            float a = cb;
#pragma unroll
            for (int k = 0; k < 25; ++k) a = fmaf(xp[t * 10 + k], xw[k], a);
            const float xc = fmaxf(a, 0.0f);
            const float tf = (float)t;
            const float a1 = tf * (1.0f / 18.0f);   // freqs = [1, 1/18]
            h[4 * t + 0] = fmaf(xc, lw0, lb0) + __sinf(tf);
            h[4 * t + 1] = fmaf(xc, lw1, lb1) + __sinf(a1);
            h[4 * t + 2] = fmaf(xc, lw2, lb2) + __cosf(tf);
            h[4 * t + 3] = fmaf(xc, lw3, lb3) + __cosf(a1);
        }
    }

    const float qscale = 0.16903085094570331f;  // 34^-0.5

    // ---------------- 2 transformer layers (rolled) ------------------------
#pragma unroll 1
    for (int l = 0; l < 2; ++l) {
        const float* Wq = wq + l * (2 * HEADD * EMBD);
        const float* Wk = wk + l * (2 * HEADD * EMBD);
        const float* Wv = wv + l * (2 * HEADD * EMBD);
        const float* Pw = proj_w + l * (EMBD * EMBD);
        const float* Pb = proj_b + l * EMBD;
        const float* W1 = ff1_w + l * (HEADD * EMBD);
        const float* b1 = ff1_b + l * HEADD;
        const float* W2 = ff2_w + l * (EMBD * HEADD);
        const float* b2 = ff2_b + l * EMBD;
        const float* g1 = ln1_g + l * EMBD; const float* e1 = ln1_b + l * EMBD;
        const float* g2 = ln2_g + l * EMBD; const float* e2 = ln2_b + l * EMBD;

        // ---- scores: q_d and k_d both streamed, no k array ----
        float wei[2][NTOK];
#pragma unroll
        for (int hh = 0; hh < 2; ++hh)
#pragma unroll
            for (int s = 0; s < NTOK; ++s) wei[hh][s] = 0.f;

#pragma unroll
        for (int hh = 0; hh < 2; ++hh) {
#pragma unroll
            for (int d = 0; d < HEADD; ++d) {
                const int o = hh * HEADD + d;
                const float qd = dot68(h, Wq + o * EMBD);
                const float kd = dot68(h, Wk + o * EMBD);
#pragma unroll
                for (int s = 0; s < NTOK; ++s)
                    wei[hh][s] = fmaf(qd, __shfl(kd, base_lane + s, 64), wei[hh][s]);
            }
        }

        // ---- softmax (q-scale folded in) ----
#pragma unroll
        for (int hh = 0; hh < 2; ++hh) {
            float m = wei[hh][0] * qscale;
#pragma unroll
            for (int s = 0; s < NTOK; ++s) { wei[hh][s] *= qscale; m = fmaxf(m, wei[hh][s]); }
            float sum = 0.f;
#pragma unroll
            for (int s = 0; s < NTOK; ++s) { wei[hh][s] = __expf(wei[hh][s] - m); sum += wei[hh][s]; }
            const float r = 1.0f / sum;
#pragma unroll
            for (int s = 0; s < NTOK; ++s) wei[hh][s] *= r;
        }

        // ---- attn: v_d streamed ----
        float attn[EMBD];
#pragma unroll
        for (int hh = 0; hh < 2; ++hh) {
#pragma unroll
            for (int d = 0; d < HEADD; ++d) {
                const int o = hh * HEADD + d;
                const float vd = dot68(h, Wv + o * EMBD);
                float a = 0.f;
#pragma unroll
                for (int s = 0; s < NTOK; ++s)
                    a = fmaf(wei[hh][s], __shfl(vd, base_lane + s, 64), a);
                attn[o] = a;
            }
        }

        // ---- proj + residual IN PLACE into h ----
#pragma unroll
        for (int o = 0; o < EMBD; ++o) {
            float a = Pb[o];
#pragma unroll
            for (int e = 0; e < EMBD; ++e) a = fmaf(attn[e], Pw[o * EMBD + e], a);
            h[o] += a;
        }
        ln68_ip(h, g1, e1);

        // ---- ff1 (relu) ----
        float z[HEADD];
#pragma unroll
        for (int f = 0; f < HEADD; ++f) {
            float a = b1[f];
#pragma unroll
            for (int e = 0; e < EMBD; ++e) a = fmaf(h[e], W1[f * EMBD + e], a);
            z[f] = fmaxf(a, 0.f);
        }

        // ---- ff2 + residual IN PLACE into h ----
#pragma unroll
        for (int o = 0; o < EMBD; ++o) {
            float a = b2[o];
#pragma unroll
            for (int f = 0; f < HEADD; ++f) a = fmaf(z[f], W2[o * HEADD + f], a);
            h[o] += a;
        }
        ln68_ip(h, g2, e2);
    }

    // ---------------- final LN ----------------
    ln68_ip(h, lnf_g, lnf_b);

    // ---------------- fc head ----------------
    float p[NTOK];
#pragma unroll
    for (int o = 0; o < NTOK; ++o) {
        float a = 0.f;
#pragma unroll
        for (int e = 0; e < EMBD; ++e)
            a = fmaf(h[e], fc_w[o * 408 + c * EMBD + e], a);
        p[o] = a;
    }
    float tot[NTOK];
#pragma unroll
    for (int o = 0; o < NTOK; ++o) {
        float a = 0.f;
#pragma unroll
        for (int t = 0; t < NTOK; ++t) a += __shfl(p[o], base_lane + t, 64);
        tot[o] = a + fc_b[o];
    }
    float myout = tot[0];
    if (c == 1) myout = tot[1];
    if (c == 2) myout = tot[2];
    if (c == 3) myout = tot[3];
    if (c == 4) myout = tot[4];
    if (c == 5) myout = tot[5];
    if (active) out[(size_t)item * 6 + c] = fmaxf(myout, 0.f);
}

extern "C" void kernel_launch(void* const* d_in, const int* in_sizes, int n_in,
                              void* d_out, int out_size, void* d_ws, size_t ws_size,
                              hipStream_t stream) {
    const float* x      = (const float*)d_in[0];
    const float* conv_w = (const float*)d_in[1];
    const float* conv_b = (const float*)d_in[2];
    const float* lemb_w = (const float*)d_in[3];
    const float* lemb_b = (const float*)d_in[4];
    const float* wq     = (const float*)d_in[5];
    const float* wk     = (const float*)d_in[6];
    const float* wv     = (const float*)d_in[7];
    const float* proj_w = (const float*)d_in[8];
    const float* proj_b = (const float*)d_in[9];
    const float* ff1_w  = (const float*)d_in[10];
    const float* ff1_b  = (const float*)d_in[11];
    const float* ff2_w  = (const float*)d_in[12];
    const float* ff2_b  = (const float*)d_in[13];
    const float* ln1_g  = (const float*)d_in[14];
    const float* ln1_b  = (const float*)d_in[15];
    const float* ln2_g  = (const float*)d_in[16];
    const float* ln2_b  = (const float*)d_in[17];
    const float* lnf_g  = (const float*)d_in[18];
    const float* lnf_b  = (const float*)d_in[19];
    const float* fc_w   = (const float*)d_in[20];
    const float* fc_b   = (const float*)d_in[21];
    float* out = (float*)d_out;

    const int B = in_sizes[0] / (6 * 37 * 5);           // 32768
    const int waves  = (B + 9) / 10;                    // 10 items per wave
    const int blocks = (waves + 3) / 4;                 // 4 waves per block

    deeparcnet_fused<<<blocks, 256, 0, stream>>>(
        x, conv_w, conv_b, lemb_w, lemb_b, wq, wk, wv, proj_w, proj_b,
        ff1_w, ff1_b, ff2_w, ff2_b, ln1_g, ln1_b, ln2_g, ln2_b,
        lnf_g, lnf_b, fc_w, fc_b, out, B);
}

// Round 4
// 1720.484 us; speedup vs baseline: 3.3335x; 3.3335x over previous
//
#include <hip/hip_runtime.h>
#include <math.h>

// DeepArcNet fused kernel, R4: small-code restructure.
// Diagnosis R1-R3: fully-unrolled kernels (~400KB straight-line code) starve
// instruction fetch (32KB I$); VALUBusy*dur >> FMA-cycle floor at low occ.
// Fix: keep ONLY h[68] (+ transient attn[68]/z[34]) in registers with
// compile-time indices; every matvec output loop is ROLLED with its result
// written to a per-lane LDS row (dynamic index -> LDS, not registers).
// Cross-token attention reads the 6 group rows from LDS at immediate offsets.
// Row stride 35 floats: score/attn read banks (35u+d)%32 are distinct across
// the 10 item-groups -> conflict-free. Item group (6 lanes) always inside one
// wave -> no __syncthreads; compiler lgkmcnt orders LDS RAW.
// Weights: wave-uniform rows -> s_load batches -> FMA with SGPR operand.

#define EMBD 68
#define NTOK 6
#define HEADD 34
#define LDSW 35                    // 34 slots + 1 pad
#define LDS_ROWS (256 + 8)         // +8 pad rows: inactive-lane reads stay in range

__device__ __forceinline__ float dot68(const float (&h)[EMBD],
                                       const float* __restrict__ w) {
    float a0 = 0.f, a1 = 0.f, a2 = 0.f, a3 = 0.f;
#pragma unroll
    for (int e = 0; e < 68; e += 4) {
        a0 = fmaf(h[e + 0], w[e + 0], a0);
        a1 = fmaf(h[e + 1], w[e + 1], a1);
        a2 = fmaf(h[e + 2], w[e + 2], a2);
        a3 = fmaf(h[e + 3], w[e + 3], a3);
    }
    return (a0 + a1) + (a2 + a3);
}

__device__ __forceinline__ float dot34(const float (&z)[HEADD],
                                       const float* __restrict__ w) {
    float a0 = 0.f, a1 = 0.f;
#pragma unroll
    for (int e = 0; e < 34; e += 2) {
        a0 = fmaf(z[e + 0], w[e + 0], a0);
        a1 = fmaf(z[e + 1], w[e + 1], a1);
    }
    return a0 + a1;
}

__device__ __forceinline__ void ln68_ip(float (&v)[EMBD],
                                        const float* __restrict__ g,
                                        const float* __restrict__ b) {
    float s1 = 0.f;
#pragma unroll
    for (int e = 0; e < EMBD; ++e) s1 += v[e];
    const float m = s1 * (1.0f / 68.0f);
    float s2 = 0.f;
#pragma unroll
    for (int e = 0; e < EMBD; ++e) { const float d = v[e] - m; s2 = fmaf(d, d, s2); }
    const float rs = rsqrtf(s2 * (1.0f / 68.0f) + 1e-5f);
#pragma unroll
    for (int e = 0; e < EMBD; ++e) v[e] = (v[e] - m) * rs * g[e] + b[e];
}

__global__ __launch_bounds__(256, 3)
void deeparcnet_fused(const float* __restrict__ x,        // [B,6,37,5]
                      const float* __restrict__ conv_w,   // [6,1,5,5]
                      const float* __restrict__ conv_b,   // [6]
                      const float* __restrict__ lemb_w,   // [6,4]
                      const float* __restrict__ lemb_b,   // [6,4]
                      const float* __restrict__ wq,       // [2,2,34,68]
                      const float* __restrict__ wk,
                      const float* __restrict__ wv,
                      const float* __restrict__ proj_w,   // [2,68,68]
                      const float* __restrict__ proj_b,   // [2,68]
                      const float* __restrict__ ff1_w,    // [2,34,68]
                      const float* __restrict__ ff1_b,    // [2,34]
                      const float* __restrict__ ff2_w,    // [2,68,34]
                      const float* __restrict__ ff2_b,    // [2,68]
                      const float* __restrict__ ln1_g, const float* __restrict__ ln1_b,
                      const float* __restrict__ ln2_g, const float* __restrict__ ln2_b,
                      const float* __restrict__ lnf_g, const float* __restrict__ lnf_b,
                      const float* __restrict__ fc_w,     // [6,408]
                      const float* __restrict__ fc_b,     // [6]
                      float* __restrict__ out,            // [B,6]
                      int B)
{
    __shared__ float lds[LDS_ROWS * LDSW];

    const int tid  = threadIdx.x;
    const int lane = tid & 63;
    const int wid  = blockIdx.x * (blockDim.x >> 6) + (tid >> 6);
    const int sub  = lane / 6;          // item slot in wave: 0..10
    const int c    = lane - sub * 6;    // token / conv channel: 0..5
    const int item = wid * 10 + sub;
    const bool active = (sub < 10) && (item < B);
    const int it = active ? item : 0;

    float* __restrict__ myrow = lds + tid * LDSW;          // lane-private row
    const float* __restrict__ grow = lds + (tid - c) * LDSW; // group base row

    // ---------------- conv encode + embed + pos -> h[68] (unrolled once) ---
    float h[EMBD];
    {
        float xw[25];
#pragma unroll
        for (int k = 0; k < 25; ++k) xw[k] = conv_w[c * 25 + k];
        const float cb = conv_b[c];
        const float* xp = x + (size_t)(it * 6 + c) * 185;

        const float lw0 = lemb_w[c * 4 + 0], lw1 = lemb_w[c * 4 + 1];
        const float lw2 = lemb_w[c * 4 + 2], lw3 = lemb_w[c * 4 + 3];
        const float lb0 = lemb_b[c * 4 + 0], lb1 = lemb_b[c * 4 + 1];
        const float lb2 = lemb_b[c * 4 + 2], lb3 = lemb_b[c * 4 + 3];

#pragma unroll
        for (int t = 0; t < 17; ++t) {
            float a = cb;
#pragma unroll
            for (int k = 0; k < 25; ++k) a = fmaf(xp[t * 10 + k], xw[k], a);
            const float xc = fmaxf(a, 0.0f);
            const float tf = (float)t;
            h[4 * t + 0] = fmaf(xc, lw0, lb0) + __sinf(tf);
            h[4 * t + 1] = fmaf(xc, lw1, lb1) + __sinf(tf * (1.0f / 18.0f));
            h[4 * t + 2] = fmaf(xc, lw2, lb2) + __cosf(tf);
            h[4 * t + 3] = fmaf(xc, lw3, lb3) + __cosf(tf * (1.0f / 18.0f));
        }
    }

    const float qscale = 0.16903085094570331f;  // 34^-0.5

#pragma unroll 1
    for (int l = 0; l < 2; ++l) {
        const float* Wq = wq + l * (2 * HEADD * EMBD);
        const float* Wk = wk + l * (2 * HEADD * EMBD);
        const float* Wv = wv + l * (2 * HEADD * EMBD);
        const float* Pw = proj_w + l * (EMBD * EMBD);
        const float* Pb = proj_b + l * EMBD;
        const float* W1 = ff1_w + l * (HEADD * EMBD);
        const float* b1 = ff1_b + l * HEADD;
        const float* W2 = ff2_w + l * (EMBD * HEADD);
        const float* b2 = ff2_b + l * EMBD;
        const float* g1 = ln1_g + l * EMBD; const float* e1 = ln1_b + l * EMBD;
        const float* g2 = ln2_g + l * EMBD; const float* e2 = ln2_b + l * EMBD;

        // ---- scores, head by head: k row -> LDS (rolled), then q stream ----
        float wei[2][NTOK];
#pragma unroll
        for (int hh = 0; hh < 2; ++hh) {
            const float* wkp = Wk + hh * HEADD * EMBD;
#pragma unroll 1
            for (int d = 0; d < HEADD; ++d)
                myrow[d] = dot68(h, wkp + d * EMBD);

            const float* wqp = Wq + hh * HEADD * EMBD;
            float w0 = 0.f, w1 = 0.f, w2 = 0.f, w3 = 0.f, w4 = 0.f, w5 = 0.f;
#pragma unroll 1
            for (int d = 0; d < HEADD; ++d) {
                const float qd = dot68(h, wqp + d * EMBD);
                w0 = fmaf(qd, grow[0 * LDSW + d], w0);
                w1 = fmaf(qd, grow[1 * LDSW + d], w1);
                w2 = fmaf(qd, grow[2 * LDSW + d], w2);
                w3 = fmaf(qd, grow[3 * LDSW + d], w3);
                w4 = fmaf(qd, grow[4 * LDSW + d], w4);
                w5 = fmaf(qd, grow[5 * LDSW + d], w5);
            }
            wei[hh][0] = w0; wei[hh][1] = w1; wei[hh][2] = w2;
            wei[hh][3] = w3; wei[hh][4] = w4; wei[hh][5] = w5;
        }

        // ---- softmax (q-scale folded) ----
#pragma unroll
        for (int hh = 0; hh < 2; ++hh) {
            float m = wei[hh][0] * qscale;
#pragma unroll
            for (int s = 0; s < NTOK; ++s) { wei[hh][s] *= qscale; m = fmaxf(m, wei[hh][s]); }
            float sum = 0.f;
#pragma unroll
            for (int s = 0; s < NTOK; ++s) { wei[hh][s] = __expf(wei[hh][s] - m); sum += wei[hh][s]; }
            const float r = 1.0f / sum;
#pragma unroll
            for (int s = 0; s < NTOK; ++s) wei[hh][s] *= r;
        }

        // ---- attn, head by head: v row -> LDS (rolled), gather (unrolled) --
        float attn[EMBD];
#pragma unroll
        for (int hh = 0; hh < 2; ++hh) {
            const float* wvp = Wv + hh * HEADD * EMBD;
#pragma unroll 1
            for (int d = 0; d < HEADD; ++d)
                myrow[d] = dot68(h, wvp + d * EMBD);
#pragma unroll
            for (int d = 0; d < HEADD; ++d) {
                float a = wei[hh][0] * grow[0 * LDSW + d];
                a = fmaf(wei[hh][1], grow[1 * LDSW + d], a);
                a = fmaf(wei[hh][2], grow[2 * LDSW + d], a);
                a = fmaf(wei[hh][3], grow[3 * LDSW + d], a);
                a = fmaf(wei[hh][4], grow[4 * LDSW + d], a);
                a = fmaf(wei[hh][5], grow[5 * LDSW + d], a);
                attn[hh * HEADD + d] = a;
            }
        }

        // ---- proj + residual (halves; rolled compute, unrolled reload) ----
#pragma unroll
        for (int q2 = 0; q2 < 2; ++q2) {
            const float* pw = Pw + q2 * HEADD * EMBD;
            const float* pb = Pb + q2 * HEADD;
#pragma unroll 1
            for (int p = 0; p < HEADD; ++p)
                myrow[p] = pb[p] + dot68(attn, pw + p * EMBD);
#pragma unroll
            for (int p = 0; p < HEADD; ++p) h[q2 * HEADD + p] += myrow[p];
        }
        ln68_ip(h, g1, e1);

        // ---- ff1 (relu) -> LDS, reload to z ----
#pragma unroll 1
        for (int f = 0; f < HEADD; ++f)
            myrow[f] = fmaxf(b1[f] + dot68(h, W1 + f * EMBD), 0.f);
        float z[HEADD];
#pragma unroll
        for (int f = 0; f < HEADD; ++f) z[f] = myrow[f];

        // ---- ff2 + residual (halves) ----
#pragma unroll
        for (int q2 = 0; q2 < 2; ++q2) {
            const float* w2p = W2 + q2 * HEADD * HEADD;
            const float* b2p = b2 + q2 * HEADD;
#pragma unroll 1
            for (int p = 0; p < HEADD; ++p)
                myrow[p] = b2p[p] + dot34(z, w2p + p * HEADD);
#pragma unroll
            for (int p = 0; p < HEADD; ++p) h[q2 * HEADD + p] += myrow[p];
        }
        ln68_ip(h, g2, e2);
    }

    // ---------------- final LN ----------------
    ln68_ip(h, lnf_g, lnf_b);

    // ---------------- fc head ----------------
    const int base_lane = sub * 6;
    float p[NTOK];
#pragma unroll
    for (int o = 0; o < NTOK; ++o) {
        float a = 0.f;
#pragma unroll
        for (int e = 0; e < EMBD; ++e)
            a = fmaf(h[e], fc_w[o * 408 + c * EMBD + e], a);
        p[o] = a;
    }
    float tot[NTOK];
#pragma unroll
    for (int o = 0; o < NTOK; ++o) {
        float a = 0.f;
#pragma unroll
        for (int t = 0; t < NTOK; ++t) a += __shfl(p[o], base_lane + t, 64);
        tot[o] = a + fc_b[o];
    }
    float myout = tot[0];
    if (c == 1) myout = tot[1];
    if (c == 2) myout = tot[2];
    if (c == 3) myout = tot[3];
    if (c == 4) myout = tot[4];
    if (c == 5) myout = tot[5];
    if (active) out[(size_t)item * 6 + c] = fmaxf(myout, 0.f);
}

extern "C" void kernel_launch(void* const* d_in, const int* in_sizes, int n_in,
                              void* d_out, int out_size, void* d_ws, size_t ws_size,
                              hipStream_t stream) {
    const float* x      = (const float*)d_in[0];
    const float* conv_w = (const float*)d_in[1];
    const float* conv_b = (const float*)d_in[2];
    const float* lemb_w = (const float*)d_in[3];
    const float* lemb_b = (const float*)d_in[4];
    const float* wq     = (const float*)d_in[5];
    const float* wk     = (const float*)d_in[6];
    const float* wv     = (const float*)d_in[7];
    const float* proj_w = (const float*)d_in[8];
    const float* proj_b = (const float*)d_in[9];
    const float* ff1_w  = (const float*)d_in[10];
    const float* ff1_b  = (const float*)d_in[11];
    const float* ff2_w  = (const float*)d_in[12];
    const float* ff2_b  = (const float*)d_in[13];
    const float* ln1_g  = (const float*)d_in[14];
    const float* ln1_b  = (const float*)d_in[15];
    const float* ln2_g  = (const float*)d_in[16];
    const float* ln2_b  = (const float*)d_in[17];
    const float* lnf_g  = (const float*)d_in[18];
    const float* lnf_b  = (const float*)d_in[19];
    const float* fc_w   = (const float*)d_in[20];
    const float* fc_b   = (const float*)d_in[21];
    float* out = (float*)d_out;

    const int B = in_sizes[0] / (6 * 37 * 5);           // 32768
    const int waves  = (B + 9) / 10;                    // 10 items per wave
    const int blocks = (waves + 3) / 4;                 // 4 waves per block

    deeparcnet_fused<<<blocks, 256, 0, stream>>>(
        x, conv_w, conv_b, lemb_w, lemb_b, wq, wk, wv, proj_w, proj_b,
        ff1_w, ff1_b, ff2_w, ff2_b, ln1_g, ln1_b, ln2_g, ln2_b,
        lnf_g, lnf_b, fc_w, fc_b, out, B);
}